// Round 1
// baseline (266.553 us; speedup 1.0000x reference)
//
#include <hip/hip_runtime.h>

typedef __attribute__((ext_vector_type(8))) short bf16x8;
typedef __attribute__((ext_vector_type(4))) float f32x4;
typedef unsigned short u16;
typedef unsigned int u32;

#define MFMA16(a, b, c) __builtin_amdgcn_mfma_f32_16x16x32_bf16((a), (b), (c), 0, 0, 0)

__device__ __forceinline__ u16 f2b(float f) {
    u32 u = __float_as_uint(f);
    u32 r = u + 0x7fffu + ((u >> 16) & 1u);
    return (u16)(r >> 16);
}

// ---------------- converts ----------------
__global__ void k_f32_to_bf16(const float* __restrict__ in, u16* __restrict__ out, int n) {
    int i = (blockIdx.x * blockDim.x + threadIdx.x) * 4;
    if (i + 3 < n) {
        float4 v = *(const float4*)(in + i);
        out[i] = f2b(v.x); out[i + 1] = f2b(v.y); out[i + 2] = f2b(v.z); out[i + 3] = f2b(v.w);
    } else {
        for (int j = i; j < n; ++j) out[j] = f2b(in[j]);
    }
}

// Wqkv_t[n][k] = n<512 ? Wq[k][n] : Wkv[k][n-512]   (n in [0,1536), k in [0,512))
__global__ void k_make_wqkv_t(const float* __restrict__ Wq, const float* __restrict__ Wkv,
                              u16* __restrict__ wt) {
    int tid = blockIdx.x * blockDim.x + threadIdx.x;  // 786432 total
    int k = tid & 511, n = tid >> 9;
    float v = (n < 512) ? Wq[k * 512 + n] : Wkv[k * 1024 + (n - 512)];
    wt[n * 512 + k] = f2b(v);
}

__global__ void k_make_wo_t(const float* __restrict__ Wo, u16* __restrict__ wt) {
    int tid = blockIdx.x * blockDim.x + threadIdx.x;  // 262144 total
    int k = tid & 511, n = tid >> 9;
    wt[n * 512 + k] = f2b(Wo[k * 512 + n]);
}

// ---------------- GEMM 1: qkv = xb @ Wqkv  (M=8192, N=1536, K=512) ----------------
// writes Q[bh][pos][d], K[bh][pos][d], V[bh][pos][d]  (bh = b*8+h, all bf16)
__global__ __launch_bounds__(256) void k_gemm_qkv(const u16* __restrict__ A, const u16* __restrict__ Bt,
                                                  u16* __restrict__ Q, u16* __restrict__ K,
                                                  u16* __restrict__ V) {
    __shared__ u16 As[128][40];
    __shared__ u16 Bs[128][40];
    const int t = threadIdx.x, l = t & 63, w = t >> 6;
    const int wr = w >> 1, wc = w & 1, l15 = l & 15, lg = l >> 4;
    const int m0 = blockIdx.x * 128, n0 = blockIdx.y * 128;
    f32x4 acc[4][4];
#pragma unroll
    for (int i = 0; i < 4; ++i)
#pragma unroll
        for (int j = 0; j < 4; ++j) acc[i][j] = (f32x4){0.f, 0.f, 0.f, 0.f};
    const int sr = t >> 1, sko = (t & 1) * 16;
    for (int k0 = 0; k0 < 512; k0 += 32) {
        __syncthreads();
        {
            const bf16x8* pa = (const bf16x8*)(A + (size_t)(m0 + sr) * 512 + k0 + sko);
            *(bf16x8*)&As[sr][sko] = pa[0];
            *(bf16x8*)&As[sr][sko + 8] = pa[1];
            const bf16x8* pb = (const bf16x8*)(Bt + (size_t)(n0 + sr) * 512 + k0 + sko);
            *(bf16x8*)&Bs[sr][sko] = pb[0];
            *(bf16x8*)&Bs[sr][sko + 8] = pb[1];
        }
        __syncthreads();
        bf16x8 af[4], bfr[4];
#pragma unroll
        for (int rt = 0; rt < 4; ++rt) af[rt] = *(const bf16x8*)&As[wr * 64 + rt * 16 + l15][lg * 8];
#pragma unroll
        for (int ct = 0; ct < 4; ++ct) bfr[ct] = *(const bf16x8*)&Bs[wc * 64 + ct * 16 + l15][lg * 8];
#pragma unroll
        for (int rt = 0; rt < 4; ++rt)
#pragma unroll
            for (int ct = 0; ct < 4; ++ct) acc[rt][ct] = MFMA16(af[rt], bfr[ct], acc[rt][ct]);
    }
#pragma unroll
    for (int rt = 0; rt < 4; ++rt)
#pragma unroll
        for (int ct = 0; ct < 4; ++ct) {
            int n = n0 + wc * 64 + ct * 16 + l15;
            int sec = n >> 9, nn = n & 511, h = nn >> 6, d = nn & 63;
            u16* dst = (sec == 0) ? Q : ((sec == 1) ? K : V);
#pragma unroll
            for (int r = 0; r < 4; ++r) {
                int m = m0 + wr * 64 + rt * 16 + lg * 4 + r;
                int b = m >> 10, pos = m & 1023, bh = b * 8 + h;
                dst[(size_t)bh * 65536 + (size_t)pos * 64 + d] = f2b(acc[rt][ct][r]);
            }
        }
}

// ---------------- V transpose: Vt[bh][d][pos] = V[bh][pos][d] ----------------
__global__ __launch_bounds__(256) void k_transpose_v(const u16* __restrict__ V, u16* __restrict__ Vt) {
    __shared__ u16 tile[64][72];
    const int bh = blockIdx.x >> 4, pt = blockIdx.x & 15;
    const int p0 = pt * 64;
    const int t = threadIdx.x, r = t >> 2, c0 = (t & 3) * 16;
    const bf16x8* src = (const bf16x8*)(V + (size_t)bh * 65536 + (size_t)(p0 + r) * 64 + c0);
    *(bf16x8*)&tile[r][c0] = src[0];
    *(bf16x8*)&tile[r][c0 + 8] = src[1];
    __syncthreads();
    union { u16 u[8]; bf16x8 v; } o0, o1;
#pragma unroll
    for (int ii = 0; ii < 8; ++ii) {
        o0.u[ii] = tile[c0 + ii][r];
        o1.u[ii] = tile[c0 + 8 + ii][r];
    }
    bf16x8* dst = (bf16x8*)(Vt + (size_t)bh * 65536 + (size_t)r * 1024 + p0 + c0);
    dst[0] = o0.v;
    dst[1] = o1.v;
}

// ---------------- flash attention with rel-pos band ----------------
// 1 wave per block, 16 query rows; iterate 16 K-tiles of 64 cols.
__global__ __launch_bounds__(64) void k_attn(const u16* __restrict__ Q, const u16* __restrict__ K,
                                             const u16* __restrict__ Vt, const u16* __restrict__ relb,
                                             u16* __restrict__ Ob) {
    __shared__ float sdist[16][84];
    __shared__ u16 plds[16][72];
    const int l = threadIdx.x, l15 = l & 15, lg = l >> 4;
    // XCD-aware swizzle: same head lands on same XCD (per-head K/V = 256KB, fits its L2)
    const int slot = blockIdx.x >> 3;
    const int bh = (blockIdx.x & 7) * 8 + (slot >> 6);
    const int i0 = (slot & 63) * 16;
    const size_t hb = (size_t)bh * 65536;

    bf16x8 qf[2];
#pragma unroll
    for (int kf = 0; kf < 2; ++kf)
        qf[kf] = *(const bf16x8*)(Q + hb + (size_t)(i0 + l15) * 64 + kf * 32 + lg * 8);

    f32x4 acc_o[4];
    float m_r[4], l_r[4];
#pragma unroll
    for (int i = 0; i < 4; ++i) {
        acc_o[i] = (f32x4){0.f, 0.f, 0.f, 0.f};
        m_r[i] = -1e30f;
        l_r[i] = 0.f;
    }

    for (int j0 = 0; j0 < 1024; j0 += 64) {
        // S = Q K^T  (16 x 64)
        f32x4 acc_s[4];
#pragma unroll
        for (int c = 0; c < 4; ++c) {
            acc_s[c] = (f32x4){0.f, 0.f, 0.f, 0.f};
#pragma unroll
            for (int kf = 0; kf < 2; ++kf) {
                bf16x8 kb = *(const bf16x8*)(K + hb + (size_t)(j0 + c * 16 + l15) * 64 + kf * 32 + lg * 8);
                acc_s[c] = MFMA16(qf[kf], kb, acc_s[c]);
            }
        }
        // S_dist[i][t] = q_i . rel_emb[clip(i0-j0-63+t)] , t in [0,80)
        const int bd = i0 - j0 - 63;
#pragma unroll
        for (int pt = 0; pt < 5; ++pt) {
            int tcol = pt * 16 + l15;
            int dd = bd + tcol;
            dd = dd < -512 ? -512 : (dd > 512 ? 512 : dd);
            const u16* rrow = relb + (size_t)(dd + 512) * 64;
            f32x4 a = (f32x4){0.f, 0.f, 0.f, 0.f};
#pragma unroll
            for (int kf = 0; kf < 2; ++kf) {
                bf16x8 rb = *(const bf16x8*)(rrow + kf * 32 + lg * 8);
                a = MFMA16(qf[kf], rb, a);
            }
#pragma unroll
            for (int r = 0; r < 4; ++r) sdist[lg * 4 + r][tcol] = a[r];
        }
        __syncthreads();
        // online softmax (rows spread: row = lg*4+rr, col = c*16+l15)
        float p[4][4];
#pragma unroll
        for (int rr = 0; rr < 4; ++rr) {
            const int row = lg * 4 + rr;
            float sv[4];
#pragma unroll
            for (int c = 0; c < 4; ++c) {
                int col = c * 16 + l15;
                sv[c] = (acc_s[c][rr] + sdist[row][row - col + 63]) * 0.125f;
            }
            float mt = fmaxf(fmaxf(sv[0], sv[1]), fmaxf(sv[2], sv[3]));
#pragma unroll
            for (int off = 1; off < 16; off <<= 1) mt = fmaxf(mt, __shfl_xor(mt, off, 64));
            float mnew = fmaxf(m_r[rr], mt);
            float alpha = __expf(m_r[rr] - mnew);
            m_r[rr] = mnew;
            float rs = 0.f;
#pragma unroll
            for (int c = 0; c < 4; ++c) {
                p[c][rr] = __expf(sv[c] - mnew);
                rs += p[c][rr];
            }
#pragma unroll
            for (int off = 1; off < 16; off <<= 1) rs += __shfl_xor(rs, off, 64);
            l_r[rr] = l_r[rr] * alpha + rs;
#pragma unroll
            for (int dt = 0; dt < 4; ++dt) acc_o[dt][rr] *= alpha;
        }
        // P -> LDS (D-layout) -> A-frags
#pragma unroll
        for (int rr = 0; rr < 4; ++rr)
#pragma unroll
            for (int c = 0; c < 4; ++c) plds[lg * 4 + rr][c * 16 + l15] = f2b(p[c][rr]);
        __syncthreads();
        bf16x8 pa[2];
#pragma unroll
        for (int kf = 0; kf < 2; ++kf) pa[kf] = *(const bf16x8*)&plds[l15][kf * 32 + lg * 8];
        // O += P @ V   (Vt[d][pos] gives contiguous B-frags)
#pragma unroll
        for (int dt = 0; dt < 4; ++dt) {
#pragma unroll
            for (int kf = 0; kf < 2; ++kf) {
                bf16x8 vb = *(const bf16x8*)(Vt + hb + (size_t)(dt * 16 + l15) * 1024 + j0 + kf * 32 + lg * 8);
                acc_o[dt] = MFMA16(pa[kf], vb, acc_o[dt]);
            }
        }
        __syncthreads();
    }
    const int b = bh >> 3, h = bh & 7;
#pragma unroll
    for (int dt = 0; dt < 4; ++dt)
#pragma unroll
        for (int rr = 0; rr < 4; ++rr) {
            int row = lg * 4 + rr;
            float v = acc_o[dt][rr] / l_r[rr];
            Ob[(size_t)(b * 1024 + i0 + row) * 512 + h * 64 + dt * 16 + l15] = f2b(v);
        }
}

// ---------------- GEMM 2: out = Ob @ Wo + bo  (M=8192, N=512, K=512, fp32 out) ----------------
__global__ __launch_bounds__(256) void k_gemm_out(const u16* __restrict__ A, const u16* __restrict__ Bt,
                                                  const float* __restrict__ bias, float* __restrict__ out) {
    __shared__ u16 As[128][40];
    __shared__ u16 Bs[128][40];
    const int t = threadIdx.x, l = t & 63, w = t >> 6;
    const int wr = w >> 1, wc = w & 1, l15 = l & 15, lg = l >> 4;
    const int m0 = blockIdx.x * 128, n0 = blockIdx.y * 128;
    f32x4 acc[4][4];
#pragma unroll
    for (int i = 0; i < 4; ++i)
#pragma unroll
        for (int j = 0; j < 4; ++j) acc[i][j] = (f32x4){0.f, 0.f, 0.f, 0.f};
    const int sr = t >> 1, sko = (t & 1) * 16;
    for (int k0 = 0; k0 < 512; k0 += 32) {
        __syncthreads();
        {
            const bf16x8* pa = (const bf16x8*)(A + (size_t)(m0 + sr) * 512 + k0 + sko);
            *(bf16x8*)&As[sr][sko] = pa[0];
            *(bf16x8*)&As[sr][sko + 8] = pa[1];
            const bf16x8* pb = (const bf16x8*)(Bt + (size_t)(n0 + sr) * 512 + k0 + sko);
            *(bf16x8*)&Bs[sr][sko] = pb[0];
            *(bf16x8*)&Bs[sr][sko + 8] = pb[1];
        }
        __syncthreads();
        bf16x8 af[4], bfr[4];
#pragma unroll
        for (int rt = 0; rt < 4; ++rt) af[rt] = *(const bf16x8*)&As[wr * 64 + rt * 16 + l15][lg * 8];
#pragma unroll
        for (int ct = 0; ct < 4; ++ct) bfr[ct] = *(const bf16x8*)&Bs[wc * 64 + ct * 16 + l15][lg * 8];
#pragma unroll
        for (int rt = 0; rt < 4; ++rt)
#pragma unroll
            for (int ct = 0; ct < 4; ++ct) acc[rt][ct] = MFMA16(af[rt], bfr[ct], acc[rt][ct]);
    }
#pragma unroll
    for (int rt = 0; rt < 4; ++rt)
#pragma unroll
        for (int ct = 0; ct < 4; ++ct) {
            int n = n0 + wc * 64 + ct * 16 + l15;
            float bv = bias[n];
#pragma unroll
            for (int r = 0; r < 4; ++r) {
                int m = m0 + wr * 64 + rt * 16 + lg * 4 + r;
                out[(size_t)m * 512 + n] = acc[rt][ct][r] + bv;
            }
        }
}

extern "C" void kernel_launch(void* const* d_in, const int* in_sizes, int n_in,
                              void* d_out, int out_size, void* d_ws, size_t ws_size,
                              hipStream_t stream) {
    const float* x    = (const float*)d_in[0];
    const float* Wq   = (const float*)d_in[1];
    const float* Wkv  = (const float*)d_in[2];
    const float* rel  = (const float*)d_in[3];
    const float* Wo   = (const float*)d_in[4];
    const float* bo   = (const float*)d_in[5];
    float* out = (float*)d_out;
    char* ws = (char*)d_ws;

    u16* xb   = (u16*)(ws + 0);          //  8,388,608 B
    u16* wqkv = (u16*)(ws + 8388608);    //  1,572,864 B
    u16* wot  = (u16*)(ws + 9961472);    //    524,288 B
    u16* relb = (u16*)(ws + 10485760);   //    131,200 B
    u16* Q    = (u16*)(ws + 10616960);   //  8,388,608 B
    u16* K    = (u16*)(ws + 19005568);   //  8,388,608 B
    u16* V    = (u16*)(ws + 27394176);   //  8,388,608 B
    u16* Vt   = (u16*)(ws + 35782784);   //  8,388,608 B
    u16* Ob   = (u16*)(ws + 44171392);   //  8,388,608 B  (total ~52.6 MB)

    k_f32_to_bf16<<<4096, 256, 0, stream>>>(x, xb, 4194304);
    k_f32_to_bf16<<<65, 256, 0, stream>>>(rel, relb, 65600);
    k_make_wqkv_t<<<3072, 256, 0, stream>>>(Wq, Wkv, wqkv);
    k_make_wo_t<<<1024, 256, 0, stream>>>(Wo, wot);
    k_gemm_qkv<<<dim3(64, 12), 256, 0, stream>>>(xb, wqkv, Q, K, V);
    k_transpose_v<<<1024, 256, 0, stream>>>(V, Vt);
    k_attn<<<4096, 64, 0, stream>>>(Q, K, Vt, relb, Ob);
    k_gemm_out<<<dim3(64, 4), 256, 0, stream>>>(Ob, wot, bo, out);
}

// Round 2
// 144.966 us; speedup vs baseline: 1.8387x; 1.8387x over previous
//
#include <hip/hip_runtime.h>

typedef __attribute__((ext_vector_type(8))) short bf16x8;
typedef __attribute__((ext_vector_type(4))) float f32x4;
typedef unsigned short u16;
typedef unsigned int u32;

#define MFMA16(a, b, c) __builtin_amdgcn_mfma_f32_16x16x32_bf16((a), (b), (c), 0, 0, 0)

__device__ __forceinline__ u16 f2b(float f) {
    u32 u = __float_as_uint(f);
    u32 r = u + 0x7fffu + ((u >> 16) & 1u);
    return (u16)(r >> 16);
}
__device__ __forceinline__ float b2f(u16 u) { return __uint_as_float(((u32)u) << 16); }

// ---------------- converts ----------------
__global__ void k_f32_to_bf16(const float* __restrict__ in, u16* __restrict__ out, int n) {
    int i = (blockIdx.x * blockDim.x + threadIdx.x) * 4;
    if (i + 3 < n) {
        float4 v = *(const float4*)(in + i);
        out[i] = f2b(v.x); out[i + 1] = f2b(v.y); out[i + 2] = f2b(v.z); out[i + 3] = f2b(v.w);
    } else {
        for (int j = i; j < n; ++j) out[j] = f2b(in[j]);
    }
}

// Wqkv_t[n][k] = n<512 ? Wq[k][n] : Wkv[k][n-512]   (n in [0,1536), k in [0,512))
__global__ void k_make_wqkv_t(const float* __restrict__ Wq, const float* __restrict__ Wkv,
                              u16* __restrict__ wt) {
    int tid = blockIdx.x * blockDim.x + threadIdx.x;  // 786432 total
    int k = tid & 511, n = tid >> 9;
    float v = (n < 512) ? Wq[k * 512 + n] : Wkv[k * 1024 + (n - 512)];
    wt[n * 512 + k] = f2b(v);
}

__global__ void k_make_wo_t(const float* __restrict__ Wo, u16* __restrict__ wt) {
    int tid = blockIdx.x * blockDim.x + threadIdx.x;  // 262144 total
    int k = tid & 511, n = tid >> 9;
    wt[n * 512 + k] = f2b(Wo[k * 512 + n]);
}

// ---------------- GEMM 1: qkv = xb @ Wqkv  (M=8192, N=1536, K=512) ----------------
__global__ __launch_bounds__(256) void k_gemm_qkv(const u16* __restrict__ A, const u16* __restrict__ Bt,
                                                  u16* __restrict__ Q, u16* __restrict__ K,
                                                  u16* __restrict__ V) {
    __shared__ u16 As[128][40];
    __shared__ u16 Bs[128][40];
    const int t = threadIdx.x, l = t & 63, w = t >> 6;
    const int wr = w >> 1, wc = w & 1, l15 = l & 15, lg = l >> 4;
    const int m0 = blockIdx.x * 128, n0 = blockIdx.y * 128;
    f32x4 acc[4][4];
#pragma unroll
    for (int i = 0; i < 4; ++i)
#pragma unroll
        for (int j = 0; j < 4; ++j) acc[i][j] = (f32x4){0.f, 0.f, 0.f, 0.f};
    const int sr = t >> 1, sko = (t & 1) * 16;
    for (int k0 = 0; k0 < 512; k0 += 32) {
        __syncthreads();
        {
            const bf16x8* pa = (const bf16x8*)(A + (size_t)(m0 + sr) * 512 + k0 + sko);
            *(bf16x8*)&As[sr][sko] = pa[0];
            *(bf16x8*)&As[sr][sko + 8] = pa[1];
            const bf16x8* pb = (const bf16x8*)(Bt + (size_t)(n0 + sr) * 512 + k0 + sko);
            *(bf16x8*)&Bs[sr][sko] = pb[0];
            *(bf16x8*)&Bs[sr][sko + 8] = pb[1];
        }
        __syncthreads();
        bf16x8 af[4], bfr[4];
#pragma unroll
        for (int rt = 0; rt < 4; ++rt) af[rt] = *(const bf16x8*)&As[wr * 64 + rt * 16 + l15][lg * 8];
#pragma unroll
        for (int ct = 0; ct < 4; ++ct) bfr[ct] = *(const bf16x8*)&Bs[wc * 64 + ct * 16 + l15][lg * 8];
#pragma unroll
        for (int rt = 0; rt < 4; ++rt)
#pragma unroll
            for (int ct = 0; ct < 4; ++ct) acc[rt][ct] = MFMA16(af[rt], bfr[ct], acc[rt][ct]);
    }
#pragma unroll
    for (int rt = 0; rt < 4; ++rt)
#pragma unroll
        for (int ct = 0; ct < 4; ++ct) {
            int n = n0 + wc * 64 + ct * 16 + l15;
            int sec = n >> 9, nn = n & 511, h = nn >> 6, d = nn & 63;
            u16* dst = (sec == 0) ? Q : ((sec == 1) ? K : V);
#pragma unroll
            for (int r = 0; r < 4; ++r) {
                int m = m0 + wr * 64 + rt * 16 + lg * 4 + r;
                int b = m >> 10, pos = m & 1023, bh = b * 8 + h;
                dst[(size_t)bh * 65536 + (size_t)pos * 64 + d] = f2b(acc[rt][ct][r]);
            }
        }
}

// ---------------- V transpose: Vt[bh][d][pos] = V[bh][pos][d] ----------------
__global__ __launch_bounds__(256) void k_transpose_v(const u16* __restrict__ V, u16* __restrict__ Vt) {
    __shared__ u16 tile[64][72];
    const int bh = blockIdx.x >> 4, pt = blockIdx.x & 15;
    const int p0 = pt * 64;
    const int t = threadIdx.x, r = t >> 2, c0 = (t & 3) * 16;
    const bf16x8* src = (const bf16x8*)(V + (size_t)bh * 65536 + (size_t)(p0 + r) * 64 + c0);
    *(bf16x8*)&tile[r][c0] = src[0];
    *(bf16x8*)&tile[r][c0 + 8] = src[1];
    __syncthreads();
    union { u16 u[8]; bf16x8 v; } o0, o1;
#pragma unroll
    for (int ii = 0; ii < 8; ++ii) {
        o0.u[ii] = tile[c0 + ii][r];
        o1.u[ii] = tile[c0 + 8 + ii][r];
    }
    bf16x8* dst = (bf16x8*)(Vt + (size_t)bh * 65536 + (size_t)r * 1024 + p0 + c0);
    dst[0] = o0.v;
    dst[1] = o1.v;
}

// ---------------- flash attention with rel-pos band ----------------
// 8 waves (512 thr) per block; block = one bh, 128 q-rows (16/wave).
// K/V tile for each j0 staged once in LDS (shared by all 8 waves), 1-tile-ahead
// register prefetch. Per-wave LDS scratch (rel band, P) needs no block barrier.
__global__ __launch_bounds__(512, 4) void k_attn(const u16* __restrict__ Q, const u16* __restrict__ K,
                                                 const u16* __restrict__ Vt, const u16* __restrict__ relb,
                                                 u16* __restrict__ Ob) {
    __shared__ u16 Ks[64][72];       // [j within tile][d], +8 pad -> 2-way max on b128 reads
    __shared__ u16 Vs[64][72];       // [d][j within tile]
    __shared__ u16 sdw[8][16][84];   // per-wave rel band, bf16, 84-col pad (conflict-free gather)
    __shared__ u16 pw[8][16][72];    // per-wave P tile
    const int t = threadIdx.x, l = t & 63, w = t >> 6;
    const int l15 = l & 15, lg = l >> 4;
    // XCD swizzle: all 8 blocks of one bh land on one XCD (per-head K/V fits its L2)
    const int g = (blockIdx.x & 7) * 64 + (blockIdx.x >> 3);
    const int bh = g >> 3;
    const int iw = (g & 7) * 128 + w * 16;   // this wave's first q-row
    const size_t hb = (size_t)bh * 65536;
    const int srow = t >> 3, scol = (t & 7) * 8;   // staging: 512 thr x 16B = 8KB tile

    bf16x8 qf[2];
#pragma unroll
    for (int kf = 0; kf < 2; ++kf)
        qf[kf] = *(const bf16x8*)(Q + hb + (size_t)(iw + l15) * 64 + kf * 32 + lg * 8);

    f32x4 acc_o[4];
    float m_r[4], l_r[4];
#pragma unroll
    for (int i = 0; i < 4; ++i) {
        acc_o[i] = (f32x4){0.f, 0.f, 0.f, 0.f};
        m_r[i] = -1e30f;
        l_r[i] = 0.f;
    }

    // prologue: stage tile 0, issue prefetch of tile 1
    bf16x8 kreg = *(const bf16x8*)(K + hb + (size_t)srow * 64 + scol);
    bf16x8 vreg = *(const bf16x8*)(Vt + hb + (size_t)srow * 1024 + scol);
    *(bf16x8*)&Ks[srow][scol] = kreg;
    *(bf16x8*)&Vs[srow][scol] = vreg;
    kreg = *(const bf16x8*)(K + hb + (size_t)(64 + srow) * 64 + scol);
    vreg = *(const bf16x8*)(Vt + hb + (size_t)srow * 1024 + 64 + scol);
    __syncthreads();

    for (int j0 = 0; j0 < 1024; j0 += 64) {
        // S = Q K^T  (16 x 64) from LDS
        f32x4 acc_s[4];
#pragma unroll
        for (int c = 0; c < 4; ++c) {
            acc_s[c] = (f32x4){0.f, 0.f, 0.f, 0.f};
#pragma unroll
            for (int kf = 0; kf < 2; ++kf) {
                bf16x8 kb = *(const bf16x8*)&Ks[c * 16 + l15][kf * 32 + lg * 8];
                acc_s[c] = MFMA16(qf[kf], kb, acc_s[c]);
            }
        }
        // rel band: sdw[w][i][t] = q_i . rel_emb[clip(iw-j0-63+t)], t in [0,80)
        const int bd = iw - j0 - 63;
#pragma unroll
        for (int pt = 0; pt < 5; ++pt) {
            int tcol = pt * 16 + l15;
            int dd = bd + tcol;
            dd = dd < -512 ? -512 : (dd > 512 ? 512 : dd);
            const u16* rrow = relb + (size_t)(dd + 512) * 64;
            f32x4 a = (f32x4){0.f, 0.f, 0.f, 0.f};
#pragma unroll
            for (int kf = 0; kf < 2; ++kf) {
                bf16x8 rb = *(const bf16x8*)(rrow + kf * 32 + lg * 8);
                a = MFMA16(qf[kf], rb, a);
            }
#pragma unroll
            for (int r = 0; r < 4; ++r) sdw[w][lg * 4 + r][tcol] = f2b(a[r]);
        }
        // online softmax (wave-local; lockstep => no barrier needed for sdw/pw)
#pragma unroll
        for (int rr = 0; rr < 4; ++rr) {
            const int row = lg * 4 + rr;
            const int tb = row + 63 - l15;
            float sv[4];
#pragma unroll
            for (int c = 0; c < 4; ++c)
                sv[c] = (acc_s[c][rr] + b2f(sdw[w][row][tb - c * 16])) * 0.125f;
            float mt = fmaxf(fmaxf(sv[0], sv[1]), fmaxf(sv[2], sv[3]));
#pragma unroll
            for (int off = 1; off < 16; off <<= 1) mt = fmaxf(mt, __shfl_xor(mt, off, 64));
            float mnew = fmaxf(m_r[rr], mt);
            float alpha = __expf(m_r[rr] - mnew);
            m_r[rr] = mnew;
            float rs = 0.f;
#pragma unroll
            for (int c = 0; c < 4; ++c) {
                float pv = __expf(sv[c] - mnew);
                rs += pv;
                pw[w][row][c * 16 + l15] = f2b(pv);
            }
#pragma unroll
            for (int off = 1; off < 16; off <<= 1) rs += __shfl_xor(rs, off, 64);
            l_r[rr] = l_r[rr] * alpha + rs;
#pragma unroll
            for (int dt = 0; dt < 4; ++dt) acc_o[dt][rr] *= alpha;
        }
        // O += P @ V
        bf16x8 pa[2];
#pragma unroll
        for (int kf = 0; kf < 2; ++kf) pa[kf] = *(const bf16x8*)&pw[w][l15][kf * 32 + lg * 8];
#pragma unroll
        for (int dt = 0; dt < 4; ++dt) {
#pragma unroll
            for (int kf = 0; kf < 2; ++kf) {
                bf16x8 vb = *(const bf16x8*)&Vs[dt * 16 + l15][kf * 32 + lg * 8];
                acc_o[dt] = MFMA16(pa[kf], vb, acc_o[dt]);
            }
        }
        __syncthreads();   // all waves done reading Ks/Vs
        if (j0 + 64 < 1024) {
            *(bf16x8*)&Ks[srow][scol] = kreg;   // implicit vmcnt wait on prefetch
            *(bf16x8*)&Vs[srow][scol] = vreg;
            if (j0 + 128 < 1024) {
                kreg = *(const bf16x8*)(K + hb + (size_t)(j0 + 128 + srow) * 64 + scol);
                vreg = *(const bf16x8*)(Vt + hb + (size_t)srow * 1024 + (j0 + 128) + scol);
            }
            __syncthreads();   // staged tile visible
        }
    }
    const int b = bh >> 3, h = bh & 7;
#pragma unroll
    for (int rr = 0; rr < 4; ++rr) {
        float rinv = 1.0f / l_r[rr];
        int row = lg * 4 + rr;
#pragma unroll
        for (int dt = 0; dt < 4; ++dt)
            Ob[(size_t)(b * 1024 + iw + row) * 512 + h * 64 + dt * 16 + l15] = f2b(acc_o[dt][rr] * rinv);
    }
}

// ---------------- GEMM 2: out = Ob @ Wo + bo  (M=8192, N=512, K=512, fp32 out) ----------------
__global__ __launch_bounds__(256) void k_gemm_out(const u16* __restrict__ A, const u16* __restrict__ Bt,
                                                  const float* __restrict__ bias, float* __restrict__ out) {
    __shared__ u16 As[128][40];
    __shared__ u16 Bs[128][40];
    const int t = threadIdx.x, l = t & 63, w = t >> 6;
    const int wr = w >> 1, wc = w & 1, l15 = l & 15, lg = l >> 4;
    const int m0 = blockIdx.x * 128, n0 = blockIdx.y * 128;
    f32x4 acc[4][4];
#pragma unroll
    for (int i = 0; i < 4; ++i)
#pragma unroll
        for (int j = 0; j < 4; ++j) acc[i][j] = (f32x4){0.f, 0.f, 0.f, 0.f};
    const int sr = t >> 1, sko = (t & 1) * 16;
    for (int k0 = 0; k0 < 512; k0 += 32) {
        __syncthreads();
        {
            const bf16x8* pa = (const bf16x8*)(A + (size_t)(m0 + sr) * 512 + k0 + sko);
            *(bf16x8*)&As[sr][sko] = pa[0];
            *(bf16x8*)&As[sr][sko + 8] = pa[1];
            const bf16x8* pb = (const bf16x8*)(Bt + (size_t)(n0 + sr) * 512 + k0 + sko);
            *(bf16x8*)&Bs[sr][sko] = pb[0];
            *(bf16x8*)&Bs[sr][sko + 8] = pb[1];
        }
        __syncthreads();
        bf16x8 af[4], bfr[4];
#pragma unroll
        for (int rt = 0; rt < 4; ++rt) af[rt] = *(const bf16x8*)&As[wr * 64 + rt * 16 + l15][lg * 8];
#pragma unroll
        for (int ct = 0; ct < 4; ++ct) bfr[ct] = *(const bf16x8*)&Bs[wc * 64 + ct * 16 + l15][lg * 8];
#pragma unroll
        for (int rt = 0; rt < 4; ++rt)
#pragma unroll
            for (int ct = 0; ct < 4; ++ct) acc[rt][ct] = MFMA16(af[rt], bfr[ct], acc[rt][ct]);
    }
#pragma unroll
    for (int rt = 0; rt < 4; ++rt)
#pragma unroll
        for (int ct = 0; ct < 4; ++ct) {
            int n = n0 + wc * 64 + ct * 16 + l15;
            float bv = bias[n];
#pragma unroll
            for (int r = 0; r < 4; ++r) {
                int m = m0 + wr * 64 + rt * 16 + lg * 4 + r;
                out[(size_t)m * 512 + n] = acc[rt][ct][r] + bv;
            }
        }
}

extern "C" void kernel_launch(void* const* d_in, const int* in_sizes, int n_in,
                              void* d_out, int out_size, void* d_ws, size_t ws_size,
                              hipStream_t stream) {
    const float* x    = (const float*)d_in[0];
    const float* Wq   = (const float*)d_in[1];
    const float* Wkv  = (const float*)d_in[2];
    const float* rel  = (const float*)d_in[3];
    const float* Wo   = (const float*)d_in[4];
    const float* bo   = (const float*)d_in[5];
    float* out = (float*)d_out;
    char* ws = (char*)d_ws;

    u16* xb   = (u16*)(ws + 0);          //  8,388,608 B
    u16* wqkv = (u16*)(ws + 8388608);    //  1,572,864 B
    u16* wot  = (u16*)(ws + 9961472);    //    524,288 B
    u16* relb = (u16*)(ws + 10485760);   //    131,200 B
    u16* Q    = (u16*)(ws + 10616960);   //  8,388,608 B
    u16* K    = (u16*)(ws + 19005568);   //  8,388,608 B
    u16* V    = (u16*)(ws + 27394176);   //  8,388,608 B
    u16* Vt   = (u16*)(ws + 35782784);   //  8,388,608 B
    u16* Ob   = (u16*)(ws + 44171392);   //  8,388,608 B  (total ~52.6 MB)

    k_f32_to_bf16<<<4096, 256, 0, stream>>>(x, xb, 4194304);
    k_f32_to_bf16<<<65, 256, 0, stream>>>(rel, relb, 65600);
    k_make_wqkv_t<<<3072, 256, 0, stream>>>(Wq, Wkv, wqkv);
    k_make_wo_t<<<1024, 256, 0, stream>>>(Wo, wot);
    k_gemm_qkv<<<dim3(64, 12), 256, 0, stream>>>(xb, wqkv, Q, K, V);
    k_transpose_v<<<1024, 256, 0, stream>>>(V, Vt);
    k_attn<<<512, 512, 0, stream>>>(Q, K, Vt, relb, Ob);
    k_gemm_out<<<dim3(64, 4), 256, 0, stream>>>(Ob, wot, bo, out);
}